// Round 3
// baseline (642.606 us; speedup 1.0000x reference)
//
#include <hip/hip_runtime.h>

#define NR 4000
#define TS 60
#define DF 6
#define HD 64
#define RB 4   // rows per GRU block

__device__ __forceinline__ float sigf(float x) { return 1.0f / (1.0f + __expf(-x)); }
__device__ __forceinline__ float tanhfast(float x) { return 1.0f - 2.0f / (1.0f + __expf(2.0f * x)); }

// ---------------------------------------------------------------------------
// Kernel 1: fused 2-layer GRU, 4 rows/block, 6 waves:
//   role 0 (waves 0,1): layer-0 recurrence, Whh0 K-split (cols 0:32 / 32:64)
//   role 1 (waves 2,3): xp1 = h0 @ Wih1^T, K-split
//   role 2 (waves 4,5): layer-1 recurrence, Whh1 K-split
// Each wave holds 3 gates x 32 cols = 96 weight floats in VGPRs (no AGPR
// round-trips). Phase p: stage1 (partial matvecs -> LDS) | barrier |
// combine (pair-sum + activations -> h bufs) | barrier.
// Timeline: combine(p) produces h0(p) and h1(p-1); 61 phases.
// ---------------------------------------------------------------------------
__global__ __launch_bounds__(384, 3) void gru_fused(
    const float* __restrict__ x,     // (4000, 360)
    const float* __restrict__ Wih0,  // (192,6)
    const float* __restrict__ Whh0,  // (192,64)
    const float* __restrict__ bih0, const float* __restrict__ bhh0,
    const float* __restrict__ Wih1,  // (192,64)
    const float* __restrict__ Whh1,  // (192,64)
    const float* __restrict__ bih1, const float* __restrict__ bhh1,
    const float* __restrict__ Wac,   // (128,)
    float* __restrict__ xh_out,      // (4000,64)
    float* __restrict__ a_out, float* __restrict__ c_out) {
  __shared__ float xlds[RB][DF * TS];   // 5760 B
  __shared__ float h0buf[RB][HD];       // 1 KB
  __shared__ float h1buf[RB][HD];       // 1 KB
  __shared__ float4 pA[2][RB][HD];      // 8 KB  slots: {hr+xr, hz+xz, hn, xn}
  __shared__ float4 pB[2][RB][HD];      // 8 KB  slots: {xr1, xz1, xn1, -}
  __shared__ float4 pC[2][RB][HD];      // 8 KB  slots: {hr1, hz1, hn1, -}

  const int r0 = blockIdx.x * RB;
  const int tid = threadIdx.x;
  const int wid = tid >> 6;
  const int lane = tid & 63;
  const int role = wid >> 1;  // 0=A,1=B,2=C
  const int hf = wid & 1;     // column half

  // stage x rows (4 rows x 360 floats, contiguous)
  for (int i = tid; i < RB * DF * TS; i += 384)
    ((float*)xlds)[i] = x[(size_t)r0 * (DF * TS) + i];
  for (int i = tid; i < RB * HD; i += 384) {
    ((float*)h0buf)[i] = 0.f;
    ((float*)h1buf)[i] = 0.f;
  }

  // weights into registers: wg[g][k] = W[(g*64+lane)][hf*32+k]
  const float* Wsel = (role == 0) ? Whh0 : ((role == 1) ? Wih1 : Whh1);
  float wg[3][32];
#pragma unroll
  for (int g = 0; g < 3; ++g) {
    const float4* src = (const float4*)(Wsel + (size_t)(g * 64 + lane) * 64 + hf * 32);
#pragma unroll
    for (int k4 = 0; k4 < 8; ++k4) {
      float4 v = src[k4];
      wg[g][4 * k4 + 0] = v.x; wg[g][4 * k4 + 1] = v.y;
      wg[g][4 * k4 + 2] = v.z; wg[g][4 * k4 + 3] = v.w;
    }
  }
  // role-A extra: Wih0 slice, wi[g*3+fl] = Wih0[(g*64+lane)][hf*3+fl]
  float wi[9];
  if (role == 0) {
#pragma unroll
    for (int g = 0; g < 3; ++g)
#pragma unroll
      for (int fl = 0; fl < 3; ++fl)
        wi[g * 3 + fl] = Wih0[(size_t)(g * 64 + lane) * DF + hf * 3 + fl];
  }

  // biases (combine-side)
  float bR = 0.f, bZ = 0.f, bXN = 0.f, bHN = 0.f, WacL = 0.f, WacH = 0.f;
  if (role == 0) {
    bR = bih0[lane] + bhh0[lane];
    bZ = bih0[64 + lane] + bhh0[64 + lane];
    bXN = bih0[128 + lane];
    bHN = bhh0[128 + lane];
  } else if (role == 2) {
    bR = bih1[lane] + bhh1[lane];
    bZ = bih1[64 + lane] + bhh1[64 + lane];
    bXN = bih1[128 + lane];
    bHN = bhh1[128 + lane];
    WacL = Wac[lane];
    WacH = Wac[64 + lane];
  }

  __syncthreads();

  for (int p = 0; p <= TS; ++p) {
    // ---------------- stage 1: partial matvecs ----------------
    if (role == 0) {
      if (p < TS) {
#pragma unroll
        for (int q = 0; q < RB; ++q) {
          const float* hsrc = &h0buf[q][hf * 32];
          float s0 = 0.f, s1 = 0.f, s2 = 0.f, s3 = 0.f;
#pragma unroll
          for (int k4 = 0; k4 < 8; ++k4) {
            float4 hv = *(const float4*)(hsrc + 4 * k4);
            s0 = fmaf(wg[0][4 * k4 + 0], hv.x, s0); s1 = fmaf(wg[1][4 * k4 + 0], hv.x, s1); s2 = fmaf(wg[2][4 * k4 + 0], hv.x, s2);
            s0 = fmaf(wg[0][4 * k4 + 1], hv.y, s0); s1 = fmaf(wg[1][4 * k4 + 1], hv.y, s1); s2 = fmaf(wg[2][4 * k4 + 1], hv.y, s2);
            s0 = fmaf(wg[0][4 * k4 + 2], hv.z, s0); s1 = fmaf(wg[1][4 * k4 + 2], hv.z, s1); s2 = fmaf(wg[2][4 * k4 + 2], hv.z, s2);
            s0 = fmaf(wg[0][4 * k4 + 3], hv.w, s0); s1 = fmaf(wg[1][4 * k4 + 3], hv.w, s1); s2 = fmaf(wg[2][4 * k4 + 3], hv.w, s2);
          }
          // fold x-projection (this half's 3 features) into slots 0,1,3
          float xa = xlds[q][(hf * 3 + 0) * TS + p];
          float xb = xlds[q][(hf * 3 + 1) * TS + p];
          float xc = xlds[q][(hf * 3 + 2) * TS + p];
          s0 = fmaf(wi[0], xa, s0); s0 = fmaf(wi[1], xb, s0); s0 = fmaf(wi[2], xc, s0);
          s1 = fmaf(wi[3], xa, s1); s1 = fmaf(wi[4], xb, s1); s1 = fmaf(wi[5], xc, s1);
          s3 = fmaf(wi[6], xa, s3); s3 = fmaf(wi[7], xb, s3); s3 = fmaf(wi[8], xc, s3);
          pA[hf][q][lane] = make_float4(s0, s1, s2, s3);
        }
      }
    } else if (role == 1) {
      if (p >= 1) {
#pragma unroll
        for (int q = 0; q < RB; ++q) {
          const float* hsrc = &h0buf[q][hf * 32];
          float s0 = 0.f, s1 = 0.f, s2 = 0.f;
#pragma unroll
          for (int k4 = 0; k4 < 8; ++k4) {
            float4 hv = *(const float4*)(hsrc + 4 * k4);
            s0 = fmaf(wg[0][4 * k4 + 0], hv.x, s0); s1 = fmaf(wg[1][4 * k4 + 0], hv.x, s1); s2 = fmaf(wg[2][4 * k4 + 0], hv.x, s2);
            s0 = fmaf(wg[0][4 * k4 + 1], hv.y, s0); s1 = fmaf(wg[1][4 * k4 + 1], hv.y, s1); s2 = fmaf(wg[2][4 * k4 + 1], hv.y, s2);
            s0 = fmaf(wg[0][4 * k4 + 2], hv.z, s0); s1 = fmaf(wg[1][4 * k4 + 2], hv.z, s1); s2 = fmaf(wg[2][4 * k4 + 2], hv.z, s2);
            s0 = fmaf(wg[0][4 * k4 + 3], hv.w, s0); s1 = fmaf(wg[1][4 * k4 + 3], hv.w, s1); s2 = fmaf(wg[2][4 * k4 + 3], hv.w, s2);
          }
          pB[hf][q][lane] = make_float4(s0, s1, s2, 0.f);
        }
      }
    } else {
      if (p >= 1) {
#pragma unroll
        for (int q = 0; q < RB; ++q) {
          const float* hsrc = &h1buf[q][hf * 32];
          float s0 = 0.f, s1 = 0.f, s2 = 0.f;
#pragma unroll
          for (int k4 = 0; k4 < 8; ++k4) {
            float4 hv = *(const float4*)(hsrc + 4 * k4);
            s0 = fmaf(wg[0][4 * k4 + 0], hv.x, s0); s1 = fmaf(wg[1][4 * k4 + 0], hv.x, s1); s2 = fmaf(wg[2][4 * k4 + 0], hv.x, s2);
            s0 = fmaf(wg[0][4 * k4 + 1], hv.y, s0); s1 = fmaf(wg[1][4 * k4 + 1], hv.y, s1); s2 = fmaf(wg[2][4 * k4 + 1], hv.y, s2);
            s0 = fmaf(wg[0][4 * k4 + 2], hv.z, s0); s1 = fmaf(wg[1][4 * k4 + 2], hv.z, s1); s2 = fmaf(wg[2][4 * k4 + 2], hv.z, s2);
            s0 = fmaf(wg[0][4 * k4 + 3], hv.w, s0); s1 = fmaf(wg[1][4 * k4 + 3], hv.w, s1); s2 = fmaf(wg[2][4 * k4 + 3], hv.w, s2);
          }
          pC[hf][q][lane] = make_float4(s0, s1, s2, 0.f);
        }
      }
    }
    __syncthreads();
    // ---------------- combine: pair-sum + activations ----------------
    if (role == 0) {
      if (p < TS) {
#pragma unroll
        for (int qq = 0; qq < 2; ++qq) {
          const int q = hf * 2 + qq;
          float4 u = pA[0][q][lane];
          float4 v = pA[1][q][lane];
          float s0 = u.x + v.x, s1 = u.y + v.y, s2 = u.z + v.z, s3 = u.w + v.w;
          float rg = sigf(s0 + bR);
          float zg = sigf(s1 + bZ);
          float ng = tanhfast(s3 + bXN + rg * (s2 + bHN));
          float hold = h0buf[q][lane];
          h0buf[q][lane] = fmaf(zg, hold - ng, ng);
        }
      }
    } else if (role == 2) {
      if (p >= 1) {
#pragma unroll
        for (int qq = 0; qq < 2; ++qq) {
          const int q = hf * 2 + qq;
          float4 xb0 = pB[0][q][lane];
          float4 xb1 = pB[1][q][lane];
          float4 hb0 = pC[0][q][lane];
          float4 hb1 = pC[1][q][lane];
          float xr = xb0.x + xb1.x, xz = xb0.y + xb1.y, xn = xb0.z + xb1.z;
          float hr = hb0.x + hb1.x, hz = hb0.y + hb1.y, hn = hb0.z + hb1.z;
          float rg = sigf(xr + hr + bR);
          float zg = sigf(xz + hz + bZ);
          float ng = tanhfast(xn + bXN + rg * (hn + bHN));
          float hold = h1buf[q][lane];
          float hnew = fmaf(zg, hold - ng, ng);
          h1buf[q][lane] = hnew;
          if (p == TS) {
            xh_out[(size_t)(r0 + q) * HD + lane] = hnew;
            float av = hnew * WacL;
            float cv = hnew * WacH;
#pragma unroll
            for (int off = 32; off; off >>= 1) {
              av += __shfl_down(av, off);
              cv += __shfl_down(cv, off);
            }
            if (lane == 0) {
              a_out[r0 + q] = av;
              c_out[r0 + q] = cv;
            }
          }
        }
      }
    }
    __syncthreads();
  }
}

// ---------------------------------------------------------------------------
// Kernel 2: masked graph attention + final FC, flash-style online softmax.
// 500 blocks x 256 threads; block = 8 rows i; j-chunks of 64.
// cArr staged to LDS once; rel values register-prefetched one chunk ahead
// (per-thread private -> no barrier needed) so HBM latency hides under PV.
// ---------------------------------------------------------------------------
#define NCH ((NR + 63) / 64)

__global__ __launch_bounds__(256) void attn_kernel(
    const float* __restrict__ rel,   // (4000,4000,3)
    const float* __restrict__ xh,    // (4000,64)
    const float* __restrict__ aArr, const float* __restrict__ cArr,
    const float* __restrict__ bSc,   // scalar
    const float* __restrict__ fcw,   // (128,)
    const float* __restrict__ fcb,   // (1,)
    float* __restrict__ pred) {
  __shared__ float xhl[64][64];  // 16KB
  __shared__ float pbuf[8][64];  // 2KB
  __shared__ float clA[NR];      // 16KB

  const int tid = threadIdx.x;
  const int il = tid >> 5;
  const int tk = tid & 31;
  const int i = blockIdx.x * 8 + il;
  const float aib = aArr[i] + bSc[0];

  for (int t = tid; t < NR; t += 256) clA[t] = cArr[t];

  // prefetch chunk 0 rel (6 floats per thread, 8-byte aligned pairs)
  float pr[6];
  {
    const int j = 2 * tk;  // < NR always for chunk 0
    const float* rp = rel + (size_t)i * (3 * NR) + (size_t)j * 3;
#pragma unroll
    for (int e = 0; e < 6; ++e) pr[e] = rp[e];
  }

  float m = -3.0e38f, s = 0.f, acc0 = 0.f, acc1 = 0.f;

  for (int c = 0; c < NCH; ++c) {
    const int j0 = c * 64;
    __syncthreads();  // previous chunk's PV fully consumed xhl
    {
      const int jj = tid >> 2, seg = tid & 3;
      const int j = j0 + jj;
      float4* dst = (float4*)&xhl[jj][seg * 16];
      if (j < NR) {
        const float4* src = (const float4*)(xh + (size_t)j * 64 + seg * 16);
#pragma unroll
        for (int q = 0; q < 4; ++q) dst[q] = src[q];
      } else {
        float4 z = {0.f, 0.f, 0.f, 0.f};
#pragma unroll
        for (int q = 0; q < 4; ++q) dst[q] = z;
      }
    }

    // scores from prefetched rel regs (no LDS dependence except clA, staged once)
    const int jb = j0 + 2 * tk;
    const bool ok = (jb < NR);
    const int jbc = ok ? jb : (NR - 2);
    float msum0 = pr[0] + pr[1] + pr[2];
    float msum1 = pr[3] + pr[4] + pr[5];
    float w0 = aib + clA[jbc];
    float w1 = aib + clA[jbc + 1];
    w0 = (w0 > 0.f) ? w0 : 0.01f * w0;
    w1 = (w1 > 0.f) ? w1 : 0.01f * w1;
    float vwa0 = (!ok) ? -3.0e37f : ((msum0 == 0.f) ? -1.0e6f : msum0 * w0);
    float vwa1 = (!ok) ? -3.0e37f : ((msum1 == 0.f) ? -1.0e6f : msum1 * w1);

    // prefetch next chunk's rel (latency hides under barrier + PV)
    if (c + 1 < NCH) {
      const int jn = j0 + 64 + 2 * tk;
      if (jn < NR) {
        const float* rp = rel + (size_t)i * (3 * NR) + (size_t)jn * 3;
#pragma unroll
        for (int e = 0; e < 6; ++e) pr[e] = rp[e];
      }
    }

    // online softmax update (within 32-lane half-wave)
    float lm = fmaxf(vwa0, vwa1);
#pragma unroll
    for (int off = 16; off; off >>= 1) lm = fmaxf(lm, __shfl_xor(lm, off, 32));
    const float mn = fmaxf(m, lm);
    const float f = __expf(m - mn);
    const float p0 = __expf(vwa0 - mn);
    const float p1 = __expf(vwa1 - mn);
    float ls = p0 + p1;
#pragma unroll
    for (int off = 16; off; off >>= 1) ls += __shfl_xor(ls, off, 32);
    s = s * f + ls;
    acc0 *= f;
    acc1 *= f;
    m = mn;
    pbuf[il][2 * tk] = p0;
    pbuf[il][2 * tk + 1] = p1;  // same half-wave writes & reads: lockstep-safe

    __syncthreads();  // xhl ready

#pragma unroll 4
    for (int j4 = 0; j4 < 16; ++j4) {
      float4 pv = *(const float4*)&pbuf[il][4 * j4];
      float2 x0 = *(const float2*)&xhl[4 * j4 + 0][2 * tk];
      float2 x1 = *(const float2*)&xhl[4 * j4 + 1][2 * tk];
      float2 x2 = *(const float2*)&xhl[4 * j4 + 2][2 * tk];
      float2 x3 = *(const float2*)&xhl[4 * j4 + 3][2 * tk];
      acc0 = fmaf(pv.x, x0.x, acc0); acc1 = fmaf(pv.x, x0.y, acc1);
      acc0 = fmaf(pv.y, x1.x, acc0); acc1 = fmaf(pv.y, x1.y, acc1);
      acc0 = fmaf(pv.z, x2.x, acc0); acc1 = fmaf(pv.z, x2.y, acc1);
      acc0 = fmaf(pv.w, x3.x, acc0); acc1 = fmaf(pv.w, x3.y, acc1);
    }
  }

  const float inv = 1.0f / s;
  const float o0 = acc0 * inv, o1 = acc1 * inv;
  float2 xi = *(const float2*)(xh + (size_t)i * 64 + 2 * tk);
  float part = fcw[2 * tk] * xi.x + fcw[2 * tk + 1] * xi.y +
               fcw[64 + 2 * tk] * o0 + fcw[64 + 2 * tk + 1] * o1;
#pragma unroll
  for (int off = 16; off; off >>= 1) part += __shfl_xor(part, off, 32);
  if (tk == 0) pred[i] = part + fcb[0];
}

extern "C" void kernel_launch(void* const* d_in, const int* in_sizes, int n_in,
                              void* d_out, int out_size, void* d_ws, size_t ws_size,
                              hipStream_t stream) {
  const float* x    = (const float*)d_in[0];
  const float* rel  = (const float*)d_in[1];
  const float* Wih0 = (const float*)d_in[2];
  const float* Whh0 = (const float*)d_in[3];
  const float* bih0 = (const float*)d_in[4];
  const float* bhh0 = (const float*)d_in[5];
  const float* Wih1 = (const float*)d_in[6];
  const float* Whh1 = (const float*)d_in[7];
  const float* bih1 = (const float*)d_in[8];
  const float* bhh1 = (const float*)d_in[9];
  const float* Wac  = (const float*)d_in[10];
  const float* bSc  = (const float*)d_in[11];
  const float* fcw  = (const float*)d_in[12];
  const float* fcb  = (const float*)d_in[13];

  float* xh = (float*)d_ws;            // 4000*64 floats
  float* aA = xh + (size_t)NR * HD;    // 4000
  float* cA = aA + NR;                 // 4000
  float* pred = (float*)d_out;

  gru_fused<<<NR / RB, 384, 0, stream>>>(x, Wih0, Whh0, bih0, bhh0, Wih1, Whh1,
                                         bih1, bhh1, Wac, xh, aA, cA);
  attn_kernel<<<NR / 8, 256, 0, stream>>>(rel, xh, aA, cA, bSc, fcw, fcb, pred);
}

// Round 4
// 282.705 us; speedup vs baseline: 2.2731x; 2.2731x over previous
//
#include <hip/hip_runtime.h>

#define NR 4000
#define TS 60
#define DF 6
#define HD 64
#define MB 16   // rows per GRU block

typedef __attribute__((ext_vector_type(8))) short bf8_t;
typedef __attribute__((ext_vector_type(4))) float f32x4;

__device__ __forceinline__ float sigf(float x) { return 1.0f / (1.0f + __expf(-x)); }
__device__ __forceinline__ float tanhfast(float x) { return 1.0f - 2.0f / (1.0f + __expf(2.0f * x)); }

__device__ __forceinline__ unsigned short f2bf(float v) {
  union { float f; unsigned u; } x; x.f = v;
  unsigned r = (x.u + 0x7fffu + ((x.u >> 16) & 1u)) >> 16;
  return (unsigned short)r;
}
__device__ __forceinline__ float bf2f(unsigned short h) {
  union { unsigned u; float f; } y; y.u = ((unsigned)h) << 16; return y.f;
}
// split 8 fp32 into hi/lo bf16 fragments (hi + lo ≈ exact to ~2^-17)
__device__ __forceinline__ void split8(const float* v, bf8_t& hi, bf8_t& lo) {
#pragma unroll
  for (int j = 0; j < 8; ++j) {
    unsigned short h = f2bf(v[j]);
    float rem = v[j] - bf2f(h);
    hi[j] = (short)h;
    lo[j] = (short)f2bf(rem);
  }
}
// swizzled LDS index for h buffers [16 rows][68 cols]: XOR bit2 of col for rows 8-15
// (keeps float4 quads intact; spreads the 16-row column reads across banks)
__device__ __forceinline__ int swz(int row, int col) {
  return row * 68 + (col ^ ((row & 8) >> 1));
}

// ---------------------------------------------------------------------------
// Kernel 1: fused 2-layer GRU via split-bf16 MFMA. 250 blocks x 16 rows,
// 4 waves; wave w owns units [16w,16w+16) of each gate. Per step:
//  xp0(VALU,K=6) -> L0 MFMA (h0 x Whh0^T) -> act -> h0->LDS -> B1 ->
//  cvt h0 frags -> xp1+L1 MFMA -> act -> h1->LDS -> B2 -> cvt h1 frags.
// Weights preloaded once as hi/lo bf16 B-frags (MFMA reads AGPRs natively).
// ---------------------------------------------------------------------------
__global__ __launch_bounds__(256, 1) void gru_mfma(
    const float* __restrict__ x,
    const float* __restrict__ Wih0, const float* __restrict__ Whh0,
    const float* __restrict__ bih0, const float* __restrict__ bhh0,
    const float* __restrict__ Wih1, const float* __restrict__ Whh1,
    const float* __restrict__ bih1, const float* __restrict__ bhh1,
    const float* __restrict__ Wac,
    float* __restrict__ xh_out, float* __restrict__ a_out, float* __restrict__ c_out) {
  __shared__ float xlds[MB * 362];   // pad 362: 4-row stride = 8 banks
  __shared__ float h0lds[16 * 68];
  __shared__ float h1lds[16 * 68];
  __shared__ float red[2][4][16];

  const int tid = threadIdx.x;
  const int w = tid >> 6;
  const int lane = tid & 63;
  const int lg = lane >> 4;   // k-group / row-group
  const int lm = lane & 15;   // unit-in-slice / A-row
  const int unit = w * 16 + lm;
  const int r0 = blockIdx.x * MB;

  // stage x rows
  for (int idx = tid; idx < MB * 360; idx += 256) {
    int rr = idx / 360, cc = idx - rr * 360;
    xlds[rr * 362 + cc] = x[(size_t)(r0 + rr) * 360 + cc];
  }

  // preload weight B-frags: wB[mat][gate][ktile][hi/lo]
  // B[k][n] = W[unit n][k]; lane: n = lm, k = kt*32 + 8*lg + j
  bf8_t wB[3][3][2][2];
  {
    const float* mats[3] = {Whh0, Wih1, Whh1};
#pragma unroll
    for (int m = 0; m < 3; ++m)
#pragma unroll
      for (int g = 0; g < 3; ++g)
#pragma unroll
        for (int kt = 0; kt < 2; ++kt) {
          const float* src = mats[m] + (size_t)(g * 64 + unit) * 64 + kt * 32 + 8 * lg;
          float v[8];
          *(float4*)&v[0] = *(const float4*)&src[0];
          *(float4*)&v[4] = *(const float4*)&src[4];
          split8(v, wB[m][g][kt][0], wB[m][g][kt][1]);
        }
  }
  // Wih0 slice (K=6, stays fp32 on VALU)
  float wih0g[3][DF];
#pragma unroll
  for (int g = 0; g < 3; ++g)
#pragma unroll
    for (int f = 0; f < DF; ++f)
      wih0g[g][f] = Wih0[(size_t)(g * 64 + unit) * DF + f];

  const float bi0r = bih0[unit], bi0z = bih0[64 + unit], bi0n = bih0[128 + unit];
  const float bh0r = bhh0[unit], bh0z = bhh0[64 + unit], bh0n = bhh0[128 + unit];
  const float c1R = bih1[unit] + bhh1[unit];
  const float c1Z = bih1[64 + unit] + bhh1[64 + unit];
  const float b1xn = bih1[128 + unit], b1hn = bhh1[128 + unit];

  bf8_t a0[2][2], a1[2][2];   // h0 / h1 A-frags [ktile][hi/lo]
  bf8_t zf = {};
#pragma unroll
  for (int kt = 0; kt < 2; ++kt)
#pragma unroll
    for (int h = 0; h < 2; ++h) { a0[kt][h] = zf; a1[kt][h] = zf; }
  float h0c[4] = {0.f, 0.f, 0.f, 0.f};  // own C-slots: rows 4*lg+i, col unit
  float h1c[4] = {0.f, 0.f, 0.f, 0.f};

  __syncthreads();

#define MF(acc, A, B) acc = __builtin_amdgcn_mfma_f32_16x16x32_bf16(A, B, acc, 0, 0, 0)
#define MF3(acc, Af, Bf) do { \
    MF(acc, Af[0], Bf[0]); MF(acc, Af[0], Bf[1]); MF(acc, Af[1], Bf[0]); } while (0)

  for (int t = 0; t < TS; ++t) {
    // ---- xp0 (VALU, K=6) as L0 C-init ----
    f32x4 aR, aZ, aN;
    float xn0[4];
#pragma unroll
    for (int i = 0; i < 4; ++i) {
      const int row = 4 * lg + i;
      const float* xb = &xlds[row * 362 + t];
      float sr = bi0r, sz = bi0z, sn = bi0n;
#pragma unroll
      for (int f = 0; f < DF; ++f) {
        float xv = xb[f * 60];
        sr = fmaf(wih0g[0][f], xv, sr);
        sz = fmaf(wih0g[1][f], xv, sz);
        sn = fmaf(wih0g[2][f], xv, sn);
      }
      aR[i] = sr + bh0r;
      aZ[i] = sz + bh0z;
      aN[i] = bh0n;
      xn0[i] = sn;
    }
    // ---- L0 MFMA: + h0(t-1) @ Whh0^T ----
#pragma unroll
    for (int kt = 0; kt < 2; ++kt) {
      MF3(aR, a0[kt], wB[0][0][kt]);
      MF3(aZ, a0[kt], wB[0][1][kt]);
      MF3(aN, a0[kt], wB[0][2][kt]);
    }
    // ---- L0 combine ----
#pragma unroll
    for (int i = 0; i < 4; ++i) {
      float r = sigf(aR[i]);
      float z = sigf(aZ[i]);
      float n = tanhfast(xn0[i] + r * aN[i]);
      h0c[i] = n + z * (h0c[i] - n);
      h0lds[swz(4 * lg + i, unit)] = h0c[i];
    }
    __syncthreads();
    // ---- cvt h0(t) frags (used by xp1 now and L0 next step) ----
#pragma unroll
    for (int kt = 0; kt < 2; ++kt) {
      float v[8];
      *(float4*)&v[0] = *(const float4*)&h0lds[swz(lm, kt * 32 + 8 * lg)];
      *(float4*)&v[4] = *(const float4*)&h0lds[swz(lm, kt * 32 + 8 * lg + 4)];
      split8(v, a0[kt][0], a0[kt][1]);
    }
    // ---- xp1 + L1 MFMA ----
    f32x4 R1, Z1, XN, HN;
#pragma unroll
    for (int i = 0; i < 4; ++i) { R1[i] = c1R; Z1[i] = c1Z; XN[i] = b1xn; HN[i] = b1hn; }
#pragma unroll
    for (int kt = 0; kt < 2; ++kt) {
      MF3(R1, a0[kt], wB[1][0][kt]);   // h0 @ Wih1^T
      MF3(Z1, a0[kt], wB[1][1][kt]);
      MF3(XN, a0[kt], wB[1][2][kt]);
      MF3(R1, a1[kt], wB[2][0][kt]);   // h1(t-1) @ Whh1^T
      MF3(Z1, a1[kt], wB[2][1][kt]);
      MF3(HN, a1[kt], wB[2][2][kt]);
    }
    // ---- L1 combine ----
#pragma unroll
    for (int i = 0; i < 4; ++i) {
      float r = sigf(R1[i]);
      float z = sigf(Z1[i]);
      float n = tanhfast(XN[i] + r * HN[i]);
      h1c[i] = n + z * (h1c[i] - n);
      h1lds[swz(4 * lg + i, unit)] = h1c[i];
    }
    __syncthreads();
    if (t < TS - 1) {
#pragma unroll
      for (int kt = 0; kt < 2; ++kt) {
        float v[8];
        *(float4*)&v[0] = *(const float4*)&h1lds[swz(lm, kt * 32 + 8 * lg)];
        *(float4*)&v[4] = *(const float4*)&h1lds[swz(lm, kt * 32 + 8 * lg + 4)];
        split8(v, a1[kt][0], a1[kt][1]);
      }
    }
  }
#undef MF3
#undef MF

  // ---- epilogue: x_hidden, a, c ----
#pragma unroll
  for (int i = 0; i < 4; ++i)
    xh_out[(size_t)(r0 + 4 * lg + i) * HD + unit] = h1c[i];

  const float WaU = Wac[unit], WcU = Wac[64 + unit];
#pragma unroll
  for (int i = 0; i < 4; ++i) {
    float av = h1c[i] * WaU, cv = h1c[i] * WcU;
#pragma unroll
    for (int off = 1; off < 16; off <<= 1) {
      av += __shfl_xor(av, off, 64);
      cv += __shfl_xor(cv, off, 64);
    }
    if (lm == 0) {
      red[0][w][4 * lg + i] = av;
      red[1][w][4 * lg + i] = cv;
    }
  }
  __syncthreads();
  if (tid < 16) {
    a_out[r0 + tid] = red[0][0][tid] + red[0][1][tid] + red[0][2][tid] + red[0][3][tid];
    c_out[r0 + tid] = red[1][0][tid] + red[1][1][tid] + red[1][2][tid] + red[1][3][tid];
  }
}

// ---------------------------------------------------------------------------
// Kernel 2: masked graph attention + final FC (unchanged from round 3).
// ---------------------------------------------------------------------------
#define NCH ((NR + 63) / 64)

__global__ __launch_bounds__(256) void attn_kernel(
    const float* __restrict__ rel,
    const float* __restrict__ xh,
    const float* __restrict__ aArr, const float* __restrict__ cArr,
    const float* __restrict__ bSc,
    const float* __restrict__ fcw,
    const float* __restrict__ fcb,
    float* __restrict__ pred) {
  __shared__ float xhl[64][64];
  __shared__ float pbuf[8][64];
  __shared__ float clA[NR];

  const int tid = threadIdx.x;
  const int il = tid >> 5;
  const int tk = tid & 31;
  const int i = blockIdx.x * 8 + il;
  const float aib = aArr[i] + bSc[0];

  for (int t = tid; t < NR; t += 256) clA[t] = cArr[t];

  float pr[6];
  {
    const int j = 2 * tk;
    const float* rp = rel + (size_t)i * (3 * NR) + (size_t)j * 3;
#pragma unroll
    for (int e = 0; e < 6; ++e) pr[e] = rp[e];
  }

  float m = -3.0e38f, s = 0.f, acc0 = 0.f, acc1 = 0.f;

  for (int c = 0; c < NCH; ++c) {
    const int j0 = c * 64;
    __syncthreads();
    {
      const int jj = tid >> 2, seg = tid & 3;
      const int j = j0 + jj;
      float4* dst = (float4*)&xhl[jj][seg * 16];
      if (j < NR) {
        const float4* src = (const float4*)(xh + (size_t)j * 64 + seg * 16);
#pragma unroll
        for (int q = 0; q < 4; ++q) dst[q] = src[q];
      } else {
        float4 z = {0.f, 0.f, 0.f, 0.f};
#pragma unroll
        for (int q = 0; q < 4; ++q) dst[q] = z;
      }
    }

    const int jb = j0 + 2 * tk;
    const bool ok = (jb < NR);
    const int jbc = ok ? jb : (NR - 2);
    float msum0 = pr[0] + pr[1] + pr[2];
    float msum1 = pr[3] + pr[4] + pr[5];
    float w0 = aib + clA[jbc];
    float w1 = aib + clA[jbc + 1];
    w0 = (w0 > 0.f) ? w0 : 0.01f * w0;
    w1 = (w1 > 0.f) ? w1 : 0.01f * w1;
    float vwa0 = (!ok) ? -3.0e37f : ((msum0 == 0.f) ? -1.0e6f : msum0 * w0);
    float vwa1 = (!ok) ? -3.0e37f : ((msum1 == 0.f) ? -1.0e6f : msum1 * w1);

    if (c + 1 < NCH) {
      const int jn = j0 + 64 + 2 * tk;
      if (jn < NR) {
        const float* rp = rel + (size_t)i * (3 * NR) + (size_t)jn * 3;
#pragma unroll
        for (int e = 0; e < 6; ++e) pr[e] = rp[e];
      }
    }

    float lm = fmaxf(vwa0, vwa1);
#pragma unroll
    for (int off = 16; off; off >>= 1) lm = fmaxf(lm, __shfl_xor(lm, off, 32));
    const float mn = fmaxf(m, lm);
    const float f = __expf(m - mn);
    const float p0 = __expf(vwa0 - mn);
    const float p1 = __expf(vwa1 - mn);
    float ls = p0 + p1;
#pragma unroll
    for (int off = 16; off; off >>= 1) ls += __shfl_xor(ls, off, 32);
    s = s * f + ls;
    acc0 *= f;
    acc1 *= f;
    m = mn;
    pbuf[il][2 * tk] = p0;
    pbuf[il][2 * tk + 1] = p1;

    __syncthreads();

#pragma unroll 4
    for (int j4 = 0; j4 < 16; ++j4) {
      float4 pv = *(const float4*)&pbuf[il][4 * j4];
      float2 x0 = *(const float2*)&xhl[4 * j4 + 0][2 * tk];
      float2 x1 = *(const float2*)&xhl[4 * j4 + 1][2 * tk];
      float2 x2 = *(const float2*)&xhl[4 * j4 + 2][2 * tk];
      float2 x3 = *(const float2*)&xhl[4 * j4 + 3][2 * tk];
      acc0 = fmaf(pv.x, x0.x, acc0); acc1 = fmaf(pv.x, x0.y, acc1);
      acc0 = fmaf(pv.y, x1.x, acc0); acc1 = fmaf(pv.y, x1.y, acc1);
      acc0 = fmaf(pv.z, x2.x, acc0); acc1 = fmaf(pv.z, x2.y, acc1);
      acc0 = fmaf(pv.w, x3.x, acc0); acc1 = fmaf(pv.w, x3.y, acc1);
    }
  }

  const float inv = 1.0f / s;
  const float o0 = acc0 * inv, o1 = acc1 * inv;
  float2 xi = *(const float2*)(xh + (size_t)i * 64 + 2 * tk);
  float part = fcw[2 * tk] * xi.x + fcw[2 * tk + 1] * xi.y +
               fcw[64 + 2 * tk] * o0 + fcw[64 + 2 * tk + 1] * o1;
#pragma unroll
  for (int off = 16; off; off >>= 1) part += __shfl_xor(part, off, 32);
  if (tk == 0) pred[i] = part + fcb[0];
}

extern "C" void kernel_launch(void* const* d_in, const int* in_sizes, int n_in,
                              void* d_out, int out_size, void* d_ws, size_t ws_size,
                              hipStream_t stream) {
  const float* x    = (const float*)d_in[0];
  const float* rel  = (const float*)d_in[1];
  const float* Wih0 = (const float*)d_in[2];
  const float* Whh0 = (const float*)d_in[3];
  const float* bih0 = (const float*)d_in[4];
  const float* bhh0 = (const float*)d_in[5];
  const float* Wih1 = (const float*)d_in[6];
  const float* Whh1 = (const float*)d_in[7];
  const float* bih1 = (const float*)d_in[8];
  const float* bhh1 = (const float*)d_in[9];
  const float* Wac  = (const float*)d_in[10];
  const float* bSc  = (const float*)d_in[11];
  const float* fcw  = (const float*)d_in[12];
  const float* fcb  = (const float*)d_in[13];

  float* xh = (float*)d_ws;
  float* aA = xh + (size_t)NR * HD;
  float* cA = aA + NR;
  float* pred = (float*)d_out;

  gru_mfma<<<NR / MB, 256, 0, stream>>>(x, Wih0, Whh0, bih0, bhh0, Wih1, Whh1,
                                        bih1, bhh1, Wac, xh, aA, cA);
  attn_kernel<<<NR / 8, 256, 0, stream>>>(rel, xh, aA, cA, bSc, fcw, fcb, pred);
}